// Round 15
// baseline (2869.154 us; speedup 1.0000x reference)
//
#include <hip/hip_runtime.h>

#define B_   128
#define S_   1024
#define I_   256
#define H_   512
#define L1_  256
#define O_   64

#define NGRP 16    // batch groups (2 per XCD -> 2 WGs/CU -> TLP)
#define WGPG 32    // workgroups per group (sync cohort)
#define MB   8     // batches per group (rows 8-15 of MFMA M zeroed)
#define NH   16    // hidden units per WG
#define SX   8     // K-steps for X part (256/32)
#define SH   16    // K-steps for H part (512/32)

#define HB_UINTS_PER_GRP 2048    // compact 8KB image (row<8 chunks only)
#define HB_UINTS_PER_BUF (NGRP * HB_UINTS_PER_GRP)

typedef __attribute__((ext_vector_type(8))) short short8;
typedef __attribute__((ext_vector_type(4))) float f4;
typedef __attribute__((ext_vector_type(4))) unsigned u32x4;

__device__ __forceinline__ unsigned short f2bf(float x) {
  unsigned u = __builtin_bit_cast(unsigned, x);
  u += 0x7FFFu + ((u >> 16) & 1u);   // RNE
  return (unsigned short)(u >> 16);
}

__device__ __forceinline__ f4 mfma_bf16(short8 a, short8 b, f4 c) {
  asm("v_mfma_f32_16x16x32_bf16 %0, %1, %2, %0" : "+v"(c) : "v"(a), "v"(b));
  return c;
}

// pack 8 fp32 -> 8 bf16 (one 16B fragment chunk) via v_cvt_pk_bf16_f32
__device__ __forceinline__ void stage_chunk(unsigned short* dst, f4 a, f4 b) {
  unsigned d0, d1, d2, d3;
  asm("v_cvt_pk_bf16_f32 %0, %1, %2" : "=v"(d0) : "v"(a[0]), "v"(a[1]));
  asm("v_cvt_pk_bf16_f32 %0, %1, %2" : "=v"(d1) : "v"(a[2]), "v"(a[3]));
  asm("v_cvt_pk_bf16_f32 %0, %1, %2" : "=v"(d2) : "v"(b[0]), "v"(b[1]));
  asm("v_cvt_pk_bf16_f32 %0, %1, %2" : "=v"(d3) : "v"(b[2]), "v"(b[3]));
  u32x4 v = {d0, d1, d2, d3};
  *(u32x4*)dst = v;
}

// R15 = R14 with ONE change: H-image LOADS are sc0 sc1 UNCONDITIONALLY.
//   Theory: R13/R14's identical failures are stale-L1 service of sc0-only
//   loads (mechanism proven by R9's poll hang). R8's 16KB image survived only
//   via L1 eviction pressure; the compact 8KB image halves fills/set and lets
//   lines live across the 2-step reuse window. sc0 sc1 loads bypass L1 but
//   still traverse the local XCD L2 (which holds the producer's sc0-dirty
//   line under l2m) -> correctness guaranteed, L2-latency data path kept.
//   H STORES stay l2m-gated sc0 (the proven WRITE_SIZE 140->9MB win).
__global__ __launch_bounds__(256, 2)
void lstm_rec(const float* __restrict__ X,
              const float* __restrict__ Wxi, const float* __restrict__ Whi, const float* __restrict__ bi,
              const float* __restrict__ Wxf, const float* __restrict__ Whf, const float* __restrict__ bfp,
              const float* __restrict__ Wxo, const float* __restrict__ Who, const float* __restrict__ bop,
              const float* __restrict__ Wxc, const float* __restrict__ Whc, const float* __restrict__ bcp,
              float* __restrict__ out, unsigned* __restrict__ flags,
              unsigned* __restrict__ xslots, unsigned* __restrict__ Hbuf)
{
  // Fragment layout (verified R1-R12): element (k,col) -> lane=((k&31)>>3)*16+col, e=k&7.
  __shared__ unsigned short AsX[2][SX][64][8];  // 16 KB  X A-fragments (dbuf)
  __shared__ unsigned short AsH[SH][64][8];     // 16 KB  H A-fragments
  __shared__ float Psw[4][16][20];              // 5 KB   per-wave P transpose (padded)
  __shared__ int mode_s;

  const int tid  = threadIdx.x;
  const int lane = tid & 63;
  const int wv   = tid >> 6;
  const int g    = blockIdx.x & 15; // batch group (same XCD for all 32 WGs: g%8)
  const int jg   = blockIdx.x >> 4; // hidden block 0..31
  const int j0   = jg * NH;
  const int b0   = g * MB;

  // ---- post our XCD id (s_getreg, m09 technique) ----
  unsigned xcc;
  asm volatile("s_getreg_b32 %0, hwreg(HW_REG_XCC_ID)" : "=s"(xcc));
  xcc &= 15u;
  if (tid == 0)
    __hip_atomic_store(xslots + g * 32 + jg, xcc + 1u,
                       __ATOMIC_RELAXED, __HIP_MEMORY_SCOPE_AGENT);

  // ---- issue X(t=0) loads NOW (1 chunk/thread); complete during weight gather ----
  const int sA   = tid >> 5;          // X K-slice 0..7
  const int pkA  = (tid >> 3) & 3;
  const int rowA = tid & 7;
  const int offA = (sA * 64 + pkA * 16 + rowA) * 8;   // ushort offset in AsX buf
  const float* bpa = X + (size_t)(b0 + rowA) * S_ * I_ + sA * 32 + pkA * 8;
  f4 ra0 = *(const f4*)(bpa);
  f4 ra1 = *(const f4*)(bpa + 4);

  const float* Whg[4] = {Whi, Whf, Who, Whc};
  const float* Wxg[4] = {Wxi, Wxf, Wxo, Wxc};
  const float* bgp[4] = {bi, bfp, bop, bcp};

  // ---- gate-interleaved column remap constants ----
  const int colL  = lane & 15;
  const int rgrpL = lane >> 4;
  const int gateL = colL >> 2;
  const int ccL   = colL & 3;
  if (tid == 0) mode_s = 0;

  // ---- hoist B-fragments DIRECTLY from global (fragment definition; no temp) ----
  // lane holds W_gate[k = s*32 + rgrpL*8 + e][j0 + wv*4 + ccL], e = 0..7
  const float* WhP = Whg[gateL];
  const float* WxP = Wxg[gateL];
  const int jcol = j0 + wv * 4 + ccL;
  short8 wx[SX], wh[SH];
  #pragma unroll
  for (int s = 0; s < SH; ++s) {
    union { unsigned short us[8]; short8 v; } t8;
    #pragma unroll
    for (int e = 0; e < 8; ++e)
      t8.us[e] = f2bf(WhP[(size_t)(s * 32 + rgrpL * 8 + e) * H_ + jcol]);
    wh[s] = t8.v;
  }
  #pragma unroll
  for (int s = 0; s < SX; ++s) {
    union { unsigned short us[8]; short8 v; } t8;
    #pragma unroll
    for (int e = 0; e < 8; ++e)
      t8.us[e] = f2bf(WxP[(size_t)(s * 32 + rgrpL * 8 + e) * H_ + jcol]);
    wx[s] = t8.v;
  }
  const float bv = bgp[gateL][jcol];

  // ---- XCD handshake (wv0 computes, relay via LDS) ----
  if (wv == 0) {
    unsigned v;
    for (;;) {
      v = __hip_atomic_load(xslots + g * 32 + (lane & 31),
                            __ATOMIC_RELAXED, __HIP_MEMORY_SCOPE_AGENT);
      if (__all((int)(v != 0u))) break;
      __builtin_amdgcn_s_sleep(1);
    }
    unsigned f0 = (unsigned)__shfl((int)v, 0, 64);
    int same = __all((int)(v == f0));
    if (lane == 0) mode_s = same;
  }
  __syncthreads();            // mode_s ready
  const bool l2m = (mode_s != 0);

  // ---- zero MFMA rows 8-15 (once) + stage AsX[0] rows 0-7 from prologue ----
  unsigned short* axbase = &AsX[0][0][0][0];
  const int AXSTRIDE = SX * 64 * 8;
  const u32x4 zz = {0u, 0u, 0u, 0u};
  #pragma unroll
  for (int it = 0; it < 2; ++it) {             // AsH high rows: 16 sl x 4 pk x 8 r
    int idx = it * 256 + tid;
    *(u32x4*)&AsH[idx >> 5][((idx >> 3) & 3) * 16 + 8 + (idx & 7)][0] = zz;
  }
  #pragma unroll
  for (int it = 0; it < 2; ++it) {             // AsX both bufs high rows
    int idx = it * 256 + tid;
    int buf = idx >> 8, rem = idx & 255;
    *(u32x4*)(axbase + buf * AXSTRIDE
              + ((rem >> 5) * 64 + ((rem >> 3) & 3) * 16 + 8 + (rem & 7)) * 8) = zz;
  }
  stage_chunk(axbase + offA, ra0, ra1);
  __syncthreads();

  float Creg = 0.f;
  const int rowG = lane >> 2;          // gate-lane mapping: lane = row*4 + c
  const int cG   = lane & 3;
  const int jG   = j0 + wv * 4 + cG;
  // compact image: chunk ci = (jG>>5)*32 + ((jG>>3)&3)*8 + rowG, dword = ci*4 + e>>1
  const int dwH  = ((jG >> 5) * 32 + ((jG >> 3) & 3) * 8 + rowG) * 4 + ((jG & 7) >> 1);

  unsigned* myflags = flags + g * 32;          // 32 per-WG flags, one line/group (R8)
  const unsigned* fp0 = myflags + (lane & 31);
  unsigned* myflagp = myflags + jg;

  for (int t = 0; t < S_; ++t) {
    const bool last = (t == S_ - 1);

    // ---- speculative flag pre-load (all waves); FAIL-SAFE init 0 ----
    unsigned fpre = 0u;
    if (t > 0)
      asm volatile("global_load_dword %0, %1, off sc0 sc1"
                   : "+v"(fpre) : "v"(fp0) : "memory");

    // ---- X-part MFMAs (2 accumulators, R8-exact) ----
    f4 acc0 = {bv, bv, bv, bv};
    f4 acc1 = {0.f, 0.f, 0.f, 0.f};
    asm("s_nop 1" : "+v"(acc0));
    asm("s_nop 1" : "+v"(acc1));
    const unsigned short* ax = axbase + (t & 1) * AXSTRIDE;
    #pragma unroll
    for (int s = 0; s < SX; ++s) {
      short8 a = *(const short8*)(ax + (s * 64 + lane) * 8);
      if (s & 1) acc1 = mfma_bf16(a, wx[s], acc1);
      else       acc0 = mfma_bf16(a, wx[s], acc0);
    }

    // ---- wait for H_t (data-dep tie + sched_barrier), copy compact 8KB image ----
    if (t > 0) {
      asm volatile("s_waitcnt vmcnt(0)" : "+v"(fpre) :: "memory");
      __builtin_amdgcn_sched_barrier(0);   // rule #18 fence
      if (!__all((int)(fpre >= (unsigned)t))) {
        for (;;) {
          unsigned v = __hip_atomic_load(fp0, __ATOMIC_RELAXED, __HIP_MEMORY_SCOPE_AGENT);
          if (__all((int)(v >= (unsigned)t))) break;
          __builtin_amdgcn_s_sleep(1);     // yield to co-resident WG
        }
      }
      const u32x4* gp = (const u32x4*)(Hbuf + (size_t)(t & 1) * HB_UINTS_PER_BUF
                                       + g * HB_UINTS_PER_GRP);
      u32x4 r0, r1;
      // sc0 sc1: bypasses L1 (stale-line hazard), still served by the local
      // XCD L2 holding the producer's sc0-dirty line under l2m.
      asm volatile(
        "global_load_dwordx4 %0, %2, off sc0 sc1\n\t"
        "global_load_dwordx4 %1, %3, off sc0 sc1\n\t"
        "s_waitcnt vmcnt(0)"
        : "=&v"(r0), "=&v"(r1)
        : "v"(gp + tid), "v"(gp + tid + 256)
        : "memory");
      // scatter chunks into fragment rows 0-7 (rows 8-15 stay zero)
      int c0 = tid, c1 = tid + 256;
      *(u32x4*)&AsH[c0 >> 5][((c0 >> 3) & 3) * 16 + (c0 & 7)][0] = r0;
      *(u32x4*)&AsH[c1 >> 5][((c1 >> 3) & 3) * 16 + (c1 & 7)][0] = r1;
    }
    __syncthreads();   // B: AsH ready

    // ---- issue X(t+1) loads (compiler sinks the waits to stage_chunk below) ----
    if (!last) {
      const float* pa = bpa + (size_t)(t + 1) * I_;
      ra0 = *(const f4*)(pa);
      ra1 = *(const f4*)(pa + 4);
    }

    // ---- H-part MFMAs ----
    if (t > 0) {
      #pragma unroll
      for (int s = 0; s < SH; ++s) {
        short8 a = *(const short8*)&AsH[s][lane][0];
        if (s & 1) acc1 = mfma_bf16(a, wh[s], acc1);
        else       acc0 = mfma_bf16(a, wh[s], acc0);
      }
    }
    asm("s_nop 7" : "+v"(acc0));
    asm("s_nop 7" : "+v"(acc1));
    f4 accs = {acc0[0] + acc1[0], acc0[1] + acc1[1], acc0[2] + acc1[2], acc0[3] + acc1[3]};

    // ---- same-wave transpose through LDS (NO barrier) ----
    *(f4*)&Psw[wv][colL][rgrpL * 4] = accs;
    asm volatile("s_waitcnt lgkmcnt(0)" ::: "memory");
    __builtin_amdgcn_sched_barrier(0);
    float pi = Psw[wv][cG][rowG];
    float pf = Psw[wv][4 + cG][rowG];
    float po = Psw[wv][8 + cG][rowG];
    float pc = Psw[wv][12 + cG][rowG];

    // ---- gates (fp32), C update ----
    float Ig = 1.f / (1.f + __expf(-pi));
    float Fg = 1.f / (1.f + __expf(-pf));
    float Og = 1.f / (1.f + __expf(-po));
    float Ct = 1.f - 2.f / (__expf(2.f * pc) + 1.f);          // tanh
    float Cn = Fg * Creg + Ig * Ct;
    Creg = Cn;
    float Hn = (1.f - 2.f / (__expf(2.f * Cn) + 1.f)) + Og;   // tanh(C) + O (addition!)

    if (!last) {
      // stage X(t+1) into AsX[(t+1)&1] (compiler waits the X loads here)
      stage_chunk(axbase + ((t + 1) & 1) * AXSTRIDE + offA, ra0, ra1);

      // H pack (cvt_pk pair with lane partner) + store; rows 0-7 only
      float Hp = __shfl_xor(Hn, 1, 64);
      if ((cG & 1) == 0 && rowG < MB) {
        unsigned packed;
        asm("v_cvt_pk_bf16_f32 %0, %1, %2" : "=v"(packed) : "v"(Hn), "v"(Hp));
        unsigned* dst = Hbuf + (size_t)((t + 1) & 1) * HB_UINTS_PER_BUF
                      + g * HB_UINTS_PER_GRP + dwH;
        if (l2m)
          asm volatile("global_store_dword %0, %1, off sc0" :: "v"(dst), "v"(packed) : "memory");
        else
          asm volatile("global_store_dword %0, %1, off sc0 sc1" :: "v"(dst), "v"(packed) : "memory");
      }
      __syncthreads();            // D: ALL waves' H stores + AsX writes drained (R8 protocol)
      if (tid == 0)
        __hip_atomic_store(myflagp, (unsigned)(t + 1),
                           __ATOMIC_RELAXED, __HIP_MEMORY_SCOPE_AGENT);
    } else if (rowG < MB) {
      out[B_ * O_ + (size_t)(b0 + rowG) * H_ + jG] = Hn;            // Hf
      out[B_ * O_ + B_ * H_ + (size_t)(b0 + rowG) * H_ + jG] = Cn;  // Cf
    }
  }
}

// Output head: h1 = relu(Hf@W_o1+b_o1); out = softmax(h1@W_o2+b_o2). One WG per batch row.
__global__ __launch_bounds__(256, 1)
void lstm_head(const float* __restrict__ Hf,
               const float* __restrict__ Wo1, const float* __restrict__ bo1,
               const float* __restrict__ Wo2, const float* __restrict__ bo2,
               float* __restrict__ outp)
{
  __shared__ float hf[H_];
  __shared__ float h1[L1_];
  const int tid = threadIdx.x;
  const int b = blockIdx.x;
  hf[tid]       = Hf[(size_t)b * H_ + tid];
  hf[tid + 256] = Hf[(size_t)b * H_ + tid + 256];
  __syncthreads();
  float a = bo1[tid];
  #pragma unroll 8
  for (int k = 0; k < H_; ++k) a = fmaf(hf[k], Wo1[(size_t)k * L1_ + tid], a);
  h1[tid] = fmaxf(a, 0.f);
  __syncthreads();
  if (tid < O_) {
    float l = bo2[tid];
    #pragma unroll 8
    for (int j = 0; j < L1_; ++j) l = fmaf(h1[j], Wo2[(size_t)j * O_ + tid], l);
    float m = l;
    #pragma unroll
    for (int off = 32; off > 0; off >>= 1) m = fmaxf(m, __shfl_xor(m, off, 64));
    float e = __expf(l - m);
    float ssum = e;
    #pragma unroll
    for (int off = 32; off > 0; off >>= 1) ssum += __shfl_xor(ssum, off, 64);
    outp[(size_t)b * O_ + tid] = e / ssum;
  }
}

extern "C" void kernel_launch(void* const* d_in, const int* in_sizes, int n_in,
                              void* d_out, int out_size, void* d_ws, size_t ws_size,
                              hipStream_t stream) {
  (void)in_sizes; (void)n_in; (void)out_size; (void)ws_size;
  const float* X   = (const float*)d_in[0];
  const float* Wxi = (const float*)d_in[1];
  const float* Whi = (const float*)d_in[2];
  const float* bi  = (const float*)d_in[3];
  const float* Wxf = (const float*)d_in[4];
  const float* Whf = (const float*)d_in[5];
  const float* bfv = (const float*)d_in[6];
  const float* Wxo = (const float*)d_in[7];
  const float* Who = (const float*)d_in[8];
  const float* bo  = (const float*)d_in[9];
  const float* Wxc = (const float*)d_in[10];
  const float* Whc = (const float*)d_in[11];
  const float* bc  = (const float*)d_in[12];
  const float* Wo1 = (const float*)d_in[13];
  const float* bo1 = (const float*)d_in[14];
  const float* Wo2 = (const float*)d_in[15];
  const float* bo2 = (const float*)d_in[16];
  float* out = (float*)d_out;

  unsigned* flags  = (unsigned*)d_ws;                     // [0,2KB): per-WG step flags
  unsigned* xslots = (unsigned*)((char*)d_ws + 2048);     // [2KB,4KB): XCD slots
  unsigned* Hbuf   = (unsigned*)((char*)d_ws + 4096);     // 2 x 128KB compact images

  (void)hipMemsetAsync(d_ws, 0, 4096, stream);  // reset flags + xslots every call
  hipLaunchKernelGGL(lstm_rec, dim3(NGRP * WGPG), dim3(256), 0, stream,
                     X, Wxi, Whi, bi, Wxf, Whf, bfv, Wxo, Who, bo, Wxc, Whc, bc,
                     out, flags, xslots, Hbuf);
  hipLaunchKernelGGL(lstm_head, dim3(B_), dim3(256), 0, stream,
                     out + B_ * O_, Wo1, bo1, Wo2, bo2, out);
}

// Round 17
// 2165.068 us; speedup vs baseline: 1.3252x; 1.3252x over previous
//
#include <hip/hip_runtime.h>

#define B_   128
#define S_   1024
#define I_   256
#define H_   512
#define L1_  256
#define O_   64

#define NGRP 8     // batch groups
#define WGPG 32    // workgroups per group (sync cohort)
#define MB   16    // batches per group
#define NH   16    // hidden units per WG
#define SX   8     // K-steps for X part (256/32)
#define SH   16    // K-steps for H part (512/32)

#define HB_UINTS_PER_BUF 32768   // 8 groups x 4096 uints (16KB fragment image per group)

typedef __attribute__((ext_vector_type(8))) short short8;
typedef __attribute__((ext_vector_type(4))) float f4;
typedef __attribute__((ext_vector_type(4))) unsigned u32x4;

__device__ __forceinline__ unsigned short f2bf(float x) {
  unsigned u = __builtin_bit_cast(unsigned, x);
  u += 0x7FFFu + ((u >> 16) & 1u);   // RNE
  return (unsigned short)(u >> 16);
}

__device__ __forceinline__ f4 mfma_bf16(short8 a, short8 b, f4 c) {
  asm("v_mfma_f32_16x16x32_bf16 %0, %1, %2, %0" : "+v"(c) : "v"(a), "v"(b));
  return c;
}

// pack 8 fp32 -> 8 bf16 (one 16B fragment chunk) via v_cvt_pk_bf16_f32
__device__ __forceinline__ void stage_chunk(unsigned short* dst, f4 a, f4 b) {
  unsigned d0, d1, d2, d3;
  asm("v_cvt_pk_bf16_f32 %0, %1, %2" : "=v"(d0) : "v"(a[0]), "v"(a[1]));
  asm("v_cvt_pk_bf16_f32 %0, %1, %2" : "=v"(d1) : "v"(a[2]), "v"(a[3]));
  asm("v_cvt_pk_bf16_f32 %0, %1, %2" : "=v"(d2) : "v"(b[0]), "v"(b[1]));
  asm("v_cvt_pk_bf16_f32 %0, %1, %2" : "=v"(d3) : "v"(b[2]), "v"(b[3]));
  u32x4 v = {d0, d1, d2, d3};
  *(u32x4*)dst = v;
}

// FINAL = R8 verbatim (session champion, 2164us, passed absmax 0.0156).
// Architecture: persistent kernel, 256 WGs = 256 CUs, 8 batch-groups x 32 WGs.
// Weights live in VGPRs (interleaved-gate column remap -> wave-self-contained
// gates, no barrier C); X double-buffered in LDS, loads pipelined one step
// ahead; H exchanged via XCD-L2 (sc0) when the runtime XCC_ID handshake shows
// the cohort shares an XCD (else LLC); per-WG step flags at system scope, one
// 128B line per group, posted by tid0 AFTER barrier D (the barrier's implicit
// drain + cache semantics are load-bearing: every alternative protocol failed
// on HW - R9 hang, R10/R11 regress, R13/R14/R16 corrupt).
// Per-step cost ~2.1us = all-to-all LLC sync floor x 1024 serial steps
// (latency-bound: MfmaUtil 7%, HBM 0.5% - not a compute/memory roofline).
__global__ __launch_bounds__(256, 1)
void lstm_rec(const float* __restrict__ X,
              const float* __restrict__ Wxi, const float* __restrict__ Whi, const float* __restrict__ bi,
              const float* __restrict__ Wxf, const float* __restrict__ Whf, const float* __restrict__ bfp,
              const float* __restrict__ Wxo, const float* __restrict__ Who, const float* __restrict__ bop,
              const float* __restrict__ Wxc, const float* __restrict__ Whc, const float* __restrict__ bcp,
              float* __restrict__ out, unsigned* __restrict__ flags,
              unsigned* __restrict__ xslots, unsigned* __restrict__ Hbuf)
{
  // Fragment layout (verified R1-R15): element (k,col) -> lane=((k&31)>>3)*16+col, e=k&7.
  __shared__ unsigned short WhF[4][SH][64][8];  // 64 KB (dead after hoist)
  __shared__ unsigned short WxF[4][SX][64][8];  // 32 KB (dead after hoist; reused as AsX[2])
  __shared__ unsigned short AsH[SH][64][8];     // 16 KB  H A-fragments
  __shared__ float Psw[4][16][20];              // 5 KB   per-wave P transpose (padded)
  __shared__ int mode_s;

  const int tid  = threadIdx.x;
  const int lane = tid & 63;
  const int wv   = tid >> 6;
  const int g    = blockIdx.x & 7;  // batch group
  const int jg   = blockIdx.x >> 3; // hidden block 0..31
  const int j0   = jg * NH;
  const int b0   = g * MB;

  // ---- post our XCD id (s_getreg, m09 technique) ----
  unsigned xcc;
  asm volatile("s_getreg_b32 %0, hwreg(HW_REG_XCC_ID)" : "=s"(xcc));
  xcc &= 15u;
  if (tid == 0)
    __hip_atomic_store(xslots + g * 32 + jg, xcc + 1u,
                       __ATOMIC_RELAXED, __HIP_MEMORY_SCOPE_AGENT);

  // ---- issue X(t=0) loads; complete during weight packing ----
  const int idxA = tid, idxB = 256 + tid;
  const int sA = idxA >> 6, posA = idxA & 63;
  const int sB = idxB >> 6, posB = idxB & 63;
  const int offA = (sA * 64 + posA) * 8;     // ushort offset of 16B chunk in AsX buf
  const int offB = (sB * 64 + posB) * 8;
  const float* bpa = X + (size_t)(b0 + (posA & 15)) * S_ * I_ + (sA * 32 + (posA >> 4) * 8);
  const float* bpb = X + (size_t)(b0 + (posB & 15)) * S_ * I_ + (sB * 32 + (posB >> 4) * 8);
  f4 ra0 = *(const f4*)(bpa);
  f4 ra1 = *(const f4*)(bpa + 4);
  f4 rb0 = *(const f4*)(bpb);
  f4 rb1 = *(const f4*)(bpb + 4);

  const float* Whg[4] = {Whi, Whf, Who, Whc};
  const float* Wxg[4] = {Wxi, Wxf, Wxo, Wxc};
  const float* bgp[4] = {bi, bfp, bop, bcp};

  // ---- one-time: pack weight slices into LDS as bf16 B-fragments (per-gate) ----
  for (int gate = 0; gate < 4; ++gate) {
    const float* Wp = Whg[gate];
    for (int it = 0; it < 32; ++it) {
      int idx = it * 256 + tid;
      int k = idx >> 4, c = idx & 15;
      WhF[gate][k >> 5][((k & 31) >> 3) * 16 + c][k & 7] = f2bf(Wp[(size_t)k * H_ + j0 + c]);
    }
    const float* Xp = Wxg[gate];
    for (int it = 0; it < 16; ++it) {
      int idx = it * 256 + tid;
      int k = idx >> 4, c = idx & 15;
      WxF[gate][k >> 5][((k & 31) >> 3) * 16 + c][k & 7] = f2bf(Xp[(size_t)k * H_ + j0 + c]);
    }
  }
  if (tid == 0) mode_s = 0;
  __syncthreads();

  // ---- hoist B-fragments with INTERLEAVED-GATE column remap ----
  // wave wv tile column col = gate*4+cc  ->  weight column j0 + wv*4 + cc of gate
  const int colL  = lane & 15;
  const int rgrpL = lane >> 4;
  const int gateL = colL >> 2;
  const int ccL   = colL & 3;
  short8 wx[SX], wh[SH];
  #pragma unroll
  for (int s = 0; s < SX; ++s)
    wx[s] = *(const short8*)&WxF[gateL][s][rgrpL * 16 + wv * 4 + ccL][0];
  #pragma unroll
  for (int s = 0; s < SH; ++s)
    wh[s] = *(const short8*)&WhF[gateL][s][rgrpL * 16 + wv * 4 + ccL][0];
  const float bv = bgp[gateL][j0 + wv * 4 + ccL];

  // ---- XCD handshake (wv0 computes, relay via LDS) ----
  if (wv == 0) {
    unsigned v;
    for (;;) {
      v = __hip_atomic_load(xslots + g * 32 + (lane & 31),
                            __ATOMIC_RELAXED, __HIP_MEMORY_SCOPE_AGENT);
      if (__all((int)(v != 0u))) break;
      __builtin_amdgcn_s_sleep(1);
    }
    unsigned f0 = (unsigned)__shfl((int)v, 0, 64);
    int same = __all((int)(v == f0));
    if (lane == 0) mode_s = same;
  }
  __syncthreads();            // hoist reads done before AsX alias writes; mode_s ready
  const bool l2m = (mode_s != 0);

  // ---- stage AsX[0] ----
  unsigned short* axbase = &WxF[0][0][0][0];   // alias: WxF is dead after hoist
  const int AXSTRIDE = SX * 64 * 8;
  stage_chunk(axbase + offA, ra0, ra1);
  stage_chunk(axbase + offB, rb0, rb1);
  __syncthreads();

  float Creg = 0.f;
  const int rowG = lane >> 2;          // gate-lane mapping: lane = row*4 + c
  const int cG   = lane & 3;
  const int jG   = j0 + wv * 4 + cG;
  const int dwH  = (((jG >> 5) * 64) + ((jG >> 3) & 3) * 16 + rowG) * 4 + ((jG & 7) >> 1);

  unsigned* myflags = flags + g * 32;          // 32 per-WG flags (one line/group)
  const unsigned* fp0 = myflags + (lane & 31);
  unsigned* myflagp = myflags + jg;

  for (int t = 0; t < S_; ++t) {
    const bool last = (t == S_ - 1);

    // ---- speculative flag pre-load (all waves); FAIL-SAFE init 0 ----
    unsigned fpre = 0u;
    if (t > 0)
      asm volatile("global_load_dword %0, %1, off sc0 sc1"
                   : "+v"(fpre) : "v"(fp0) : "memory");

    // ---- X-part MFMAs (2 accumulators) ----
    f4 acc0 = {bv, bv, bv, bv};
    f4 acc1 = {0.f, 0.f, 0.f, 0.f};
    asm("s_nop 1" : "+v"(acc0));
    asm("s_nop 1" : "+v"(acc1));
    const unsigned short* ax = axbase + (t & 1) * AXSTRIDE;
    #pragma unroll
    for (int s = 0; s < SX; ++s) {
      short8 a = *(const short8*)(ax + (s * 64 + lane) * 8);
      if (s & 1) acc1 = mfma_bf16(a, wx[s], acc1);
      else       acc0 = mfma_bf16(a, wx[s], acc0);
    }

    // ---- wait for H_t (data-dep tie + sched_barrier, R5-proven), load H image ----
    if (t > 0) {
      asm volatile("s_waitcnt vmcnt(0)" : "+v"(fpre) :: "memory");
      __builtin_amdgcn_sched_barrier(0);   // rule #18 fence
      if (!__all((int)(fpre >= (unsigned)t))) {
        for (;;) {
          unsigned v = __hip_atomic_load(fp0, __ATOMIC_RELAXED, __HIP_MEMORY_SCOPE_AGENT);
          if (__all((int)(v >= (unsigned)t))) break;
          __builtin_amdgcn_s_sleep(1);
        }
      }
      const u32x4* gp = (const u32x4*)(Hbuf + (size_t)(t & 1) * HB_UINTS_PER_BUF + g * 4096);
      u32x4 r0, r1, r2, r3;
      if (l2m) {
        asm volatile(
          "global_load_dwordx4 %0, %4, off sc0\n\t"
          "global_load_dwordx4 %1, %5, off sc0\n\t"
          "global_load_dwordx4 %2, %6, off sc0\n\t"
          "global_load_dwordx4 %3, %7, off sc0\n\t"
          "s_waitcnt vmcnt(0)"
          : "=&v"(r0), "=&v"(r1), "=&v"(r2), "=&v"(r3)
          : "v"(gp + tid), "v"(gp + tid + 256), "v"(gp + tid + 512), "v"(gp + tid + 768)
          : "memory");
      } else {
        asm volatile(
          "global_load_dwordx4 %0, %4, off sc0 sc1\n\t"
          "global_load_dwordx4 %1, %5, off sc0 sc1\n\t"
          "global_load_dwordx4 %2, %6, off sc0 sc1\n\t"
          "global_load_dwordx4 %3, %7, off sc0 sc1\n\t"
          "s_waitcnt vmcnt(0)"
          : "=&v"(r0), "=&v"(r1), "=&v"(r2), "=&v"(r3)
          : "v"(gp + tid), "v"(gp + tid + 256), "v"(gp + tid + 512), "v"(gp + tid + 768)
          : "memory");
      }
      u32x4* lp = (u32x4*)&AsH[0][0][0];
      lp[tid]       = r0;
      lp[tid + 256] = r1;
      lp[tid + 512] = r2;
      lp[tid + 768] = r3;
    }
    __syncthreads();   // B: AsH ready

    // ---- issue X(t+1) loads (compiler sinks the waits to stage_chunk below) ----
    if (!last) {
      const float* pa  = bpa + (size_t)(t + 1) * I_;
      const float* pb2 = bpb + (size_t)(t + 1) * I_;
      ra0 = *(const f4*)(pa);
      ra1 = *(const f4*)(pa + 4);
      rb0 = *(const f4*)(pb2);
      rb1 = *(const f4*)(pb2 + 4);
    }

    // ---- H-part MFMAs ----
    if (t > 0) {
      #pragma unroll
      for (int s = 0; s < SH; ++s) {
        short8 a = *(const short8*)&AsH[s][lane][0];
        if (s & 1) acc1 = mfma_bf16(a, wh[s], acc1);
        else       acc0 = mfma_bf16(a, wh[s], acc0);
      }
    }
    asm("s_nop 7" : "+v"(acc0));
    asm("s_nop 7" : "+v"(acc1));
    f4 accs = {acc0[0] + acc1[0], acc0[1] + acc1[1], acc0[2] + acc1[2], acc0[3] + acc1[3]};

    // ---- same-wave transpose through LDS (NO barrier) ----
    *(f4*)&Psw[wv][colL][rgrpL * 4] = accs;
    asm volatile("s_waitcnt lgkmcnt(0)" ::: "memory");
    __builtin_amdgcn_sched_barrier(0);
    float pi = Psw[wv][cG][rowG];
    float pf = Psw[wv][4 + cG][rowG];
    float po = Psw[wv][8 + cG][rowG];
    float pc = Psw[wv][12 + cG][rowG];

    // ---- gates (fp32), C update ----
    float Ig = 1.f / (1.f + __expf(-pi));
    float Fg = 1.f / (1.f + __expf(-pf));
    float Og = 1.f / (1.f + __expf(-po));
    float Ct = 1.f - 2.f / (__expf(2.f * pc) + 1.f);          // tanh
    float Cn = Fg * Creg + Ig * Ct;
    Creg = Cn;
    float Hn = (1.f - 2.f / (__expf(2.f * Cn) + 1.f)) + Og;   // tanh(C) + O (addition!)

    if (!last) {
      // stage X(t+1) into AsX[(t+1)&1] (compiler waits the X loads here)
      unsigned short* axw = axbase + ((t + 1) & 1) * AXSTRIDE;
      stage_chunk(axw + offA, ra0, ra1);
      stage_chunk(axw + offB, rb0, rb1);

      // H pack (cvt_pk pair with lane partner) + store
      float Hp = __shfl_xor(Hn, 1, 64);
      if ((cG & 1) == 0) {
        unsigned packed;
        asm("v_cvt_pk_bf16_f32 %0, %1, %2" : "=v"(packed) : "v"(Hn), "v"(Hp));
        unsigned* dst = Hbuf + (size_t)((t + 1) & 1) * HB_UINTS_PER_BUF + g * 4096 + dwH;
        if (l2m)
          asm volatile("global_store_dword %0, %1, off sc0" :: "v"(dst), "v"(packed) : "memory");
        else
          asm volatile("global_store_dword %0, %1, off sc0 sc1" :: "v"(dst), "v"(packed) : "memory");
      }
      __syncthreads();            // D: ALL waves' H stores + AsX writes drained (load-bearing)
      if (tid == 0)
        __hip_atomic_store(myflagp, (unsigned)(t + 1),
                           __ATOMIC_RELAXED, __HIP_MEMORY_SCOPE_AGENT);
    } else {
      out[B_ * O_ + (size_t)(b0 + rowG) * H_ + jG] = Hn;            // Hf
      out[B_ * O_ + B_ * H_ + (size_t)(b0 + rowG) * H_ + jG] = Cn;  // Cf
    }
  }
}

// Output head: h1 = relu(Hf@W_o1+b_o1); out = softmax(h1@W_o2+b_o2). One WG per batch row.
__global__ __launch_bounds__(256, 1)
void lstm_head(const float* __restrict__ Hf,
               const float* __restrict__ Wo1, const float* __restrict__ bo1,
               const float* __restrict__ Wo2, const float* __restrict__ bo2,
               float* __restrict__ outp)
{
  __shared__ float hf[H_];
  __shared__ float h1[L1_];
  const int tid = threadIdx.x;
  const int b = blockIdx.x;
  hf[tid]       = Hf[(size_t)b * H_ + tid];
  hf[tid + 256] = Hf[(size_t)b * H_ + tid + 256];
  __syncthreads();
  float a = bo1[tid];
  #pragma unroll 8
  for (int k = 0; k < H_; ++k) a = fmaf(hf[k], Wo1[(size_t)k * L1_ + tid], a);
  h1[tid] = fmaxf(a, 0.f);
  __syncthreads();
  if (tid < O_) {
    float l = bo2[tid];
    #pragma unroll 8
    for (int j = 0; j < L1_; ++j) l = fmaf(h1[j], Wo2[(size_t)j * O_ + tid], l);
    float m = l;
    #pragma unroll
    for (int off = 32; off > 0; off >>= 1) m = fmaxf(m, __shfl_xor(m, off, 64));
    float e = __expf(l - m);
    float ssum = e;
    #pragma unroll
    for (int off = 32; off > 0; off >>= 1) ssum += __shfl_xor(ssum, off, 64);
    outp[(size_t)b * O_ + tid] = e / ssum;
  }
}

extern "C" void kernel_launch(void* const* d_in, const int* in_sizes, int n_in,
                              void* d_out, int out_size, void* d_ws, size_t ws_size,
                              hipStream_t stream) {
  (void)in_sizes; (void)n_in; (void)out_size; (void)ws_size;
  const float* X   = (const float*)d_in[0];
  const float* Wxi = (const float*)d_in[1];
  const float* Whi = (const float*)d_in[2];
  const float* bi  = (const float*)d_in[3];
  const float* Wxf = (const float*)d_in[4];
  const float* Whf = (const float*)d_in[5];
  const float* bfv = (const float*)d_in[6];
  const float* Wxo = (const float*)d_in[7];
  const float* Who = (const float*)d_in[8];
  const float* bo  = (const float*)d_in[9];
  const float* Wxc = (const float*)d_in[10];
  const float* Whc = (const float*)d_in[11];
  const float* bc  = (const float*)d_in[12];
  const float* Wo1 = (const float*)d_in[13];
  const float* bo1 = (const float*)d_in[14];
  const float* Wo2 = (const float*)d_in[15];
  const float* bo2 = (const float*)d_in[16];
  float* out = (float*)d_out;

  unsigned* flags  = (unsigned*)d_ws;                     // [0,1KB): per-WG step flags
  unsigned* xslots = (unsigned*)((char*)d_ws + 1024);     // [1KB,2KB): XCD slots
  unsigned* Hbuf   = (unsigned*)((char*)d_ws + 2048);     // 2 x 128KB fragment images

  (void)hipMemsetAsync(d_ws, 0, 2048, stream);  // reset flags + xslots every call
  hipLaunchKernelGGL(lstm_rec, dim3(NGRP * WGPG), dim3(256), 0, stream,
                     X, Wxi, Whi, bi, Wxf, Whf, bfv, Wxo, Who, bo, Wxc, Whc, bc,
                     out, flags, xslots, Hbuf);
  hipLaunchKernelGGL(lstm_head, dim3(B_), dim3(256), 0, stream,
                     out + B_ * O_, Wo1, bo1, Wo2, bo2, out);
}